// Round 10
// baseline (139.382 us; speedup 1.0000x reference)
//
#include <hip/hip_runtime.h>
#include <math.h>

#define N_G 512
#define IMG_H 324
#define IMG_W 332
#define N_C 120
#define HW (IMG_H*IMG_W)
#define CHUNK 32               // k-tile (hits per chunk)
#define TSX 11                 // tiles in x (32 px)
#define TSY 81                 // tiles in y (4 px)
#define NT (TSX*TSY)
#define NBLK 768               // 3 persistent blocks per CU

typedef __bf16 bf16x8 __attribute__((ext_vector_type(8)));
typedef float  f32x4  __attribute__((ext_vector_type(4)));

__device__ __forceinline__ unsigned pk2(float a, float b) {
  __bf16 x = (__bf16)a, y = (__bf16)b;
  unsigned short ux = __builtin_bit_cast(unsigned short, x);
  unsigned short uy = __builtin_bit_cast(unsigned short, y);
  return (unsigned)ux | ((unsigned)uy << 16);
}

// ws layout (depth-sorted by k_prep):
//   bb  : [512] float4 {xmin,xmax,ymin,ymax}  cull bbox (6-sigma; empty if skip)
//   ps  : [512][8] {sx, sy, c00s, c11s, log2op, depth, (src*120)_bits, 0}
//   cnt : tile-queue counter (zeroed each launch)
__global__ __launch_bounds__(512) void k_prep(
    const float* __restrict__ pos, const float* __restrict__ scales,
    const float* __restrict__ opac, const float* __restrict__ K,
    const float* __restrict__ E,
    float4* __restrict__ bb, float* __restrict__ ps, int* __restrict__ cnt)
{
  __shared__ float key[N_G];
  const int i = threadIdx.x;
  if (i == 0) *cnt = 0;

  float p0 = pos[i*3+0], p1 = pos[i*3+1], p2 = pos[i*3+2];
  float cam0 = E[0]*p0 + E[1]*p1 + E[2]*p2  + E[3];
  float cam1 = E[4]*p0 + E[5]*p1 + E[6]*p2  + E[7];
  float cam2 = E[8]*p0 + E[9]*p1 + E[10]*p2 + E[11];
  float pr0 = K[0]*cam0 + K[1]*cam1 + K[2]*cam2;
  float pr1 = K[3]*cam0 + K[4]*cam1 + K[5]*cam2;
  float pr2 = K[6]*cam0 + K[7]*cam1 + K[8]*cam2;
  float inv = 1.0f/(pr2 + 1e-6f);
  float sx = pr0*inv, sy = pr1*inv;
  float depth = cam2;

  bool valid = (depth > 0.01f) && (depth < 100.0f)
            && (sx > -100.0f) && (sx < (float)IMG_W + 100.0f)
            && (sy > -100.0f) && (sy < (float)IMG_H + 100.0f);
  bool off = (sx < -(float)IMG_W) || (sx > 2.0f*(float)IMG_W)
          || (sy < -(float)IMG_H) || (sy > 2.0f*(float)IMG_H);
  bool skip = off || (!valid);

  float s0 = scales[i*3+0], s1 = scales[i*3+1];
  float v0 = s0*s0 + 1e-4f, v1 = s1*s1 + 1e-4f;
  const float HL2E = 0.72134752f;              // 0.5*log2(e)
  float c00s = HL2E/v0, c11s = HL2E/v1;
  float op = skip ? 0.0f : opac[i];
  float l2op = __log2f(op);                    // op=0 -> -inf -> exp2 -> 0
  float rx = 6.0f*sqrtf(v0);                   // mahal cutoff 36 (6 sigma)
  float ry = 6.0f*sqrtf(v1);
  float xmin = skip ?  1e9f : sx - rx;
  float xmax = skip ? -1e9f : sx + rx;
  float ymin = skip ?  1e9f : sy - ry;
  float ymax = skip ? -1e9f : sy + ry;

  key[i] = depth;
  __syncthreads();

  int rank = 0;
  #pragma unroll 4
  for (int j = 0; j < N_G; j += 4) {
    float4 k4 = *(const float4*)&key[j];
    rank += (k4.x < depth || (k4.x == depth && j+0 < i)) ? 1 : 0;
    rank += (k4.y < depth || (k4.y == depth && j+1 < i)) ? 1 : 0;
    rank += (k4.z < depth || (k4.z == depth && j+2 < i)) ? 1 : 0;
    rank += (k4.w < depth || (k4.w == depth && j+3 < i)) ? 1 : 0;
  }

  bb[rank] = make_float4(xmin, xmax, ymin, ymax);
  *(float4*)&ps[rank*8]   = make_float4(sx, sy, c00s, c11s);
  *(float4*)&ps[rank*8+4] = make_float4(l2op, depth, __int_as_float(i*N_C), 0.0f);
}

// Persistent blocks pull 32x8... (32x4) px tiles center-out. 2 px/thread.
// Chunks of 32 hits:
//   1a: araw[j][px] fp32 -> buf; spec rows -> At bf16 (xor-swizzled)
//   1b: 4-wave segmented scan (8 serial steps each) -> w bf16 -> Bt
//   2 : MFMA GEMM D[128c][128px] += At * Bt
#define MFMA(a,b,c) __builtin_amdgcn_mfma_f32_16x16x32_bf16((a),(b),(c),0,0,0)

__global__ __launch_bounds__(256, 3) void k_render(
    const float4* __restrict__ bb, const float* __restrict__ ps,
    int* __restrict__ cnt, const float* __restrict__ spec,
    const float* __restrict__ tm, float* __restrict__ out)
{
  __shared__ unsigned short hlist[N_G];   // 1 KB
  __shared__ float  buf[CHUNK*128];       // araw [j][px]      16 KB
  __shared__ __bf16 At[128*CHUNK];        // spec^T [c][k]      8 KB (swizzled)
  __shared__ __bf16 Bt[128*CHUNK];        // w      [px][k]     8 KB (swizzled)
  __shared__ float  dep[CHUNK];
  __shared__ float  tmL[128];
  __shared__ float  Tcar[128];
  __shared__ float  seg[4][128];
  __shared__ float  dpar[4][128];
  __shared__ int    wcnt[4];
  __shared__ int    stile;

  const int tid  = threadIdx.x;
  const int w    = tid >> 6;
  const int lane = tid & 63;
  const int cl   = lane & 15;
  const int quad = lane >> 4;
  const unsigned long long ltm = (1ull << lane) - 1ull;
  const int mc0 = w*32, mc1 = w*32 + 16;   // this wave's channel tiles

  if (tid < N_C) tmL[tid] = tm[tid];
  else if (tid < 128) tmL[tid] = 0.0f;

  for (;;) {
    if (tid == 0) stile = atomicAdd(cnt, 1);
    __syncthreads();
    const int t = stile;
    if (t >= NT) break;
    // center-out bijection: hot center tiles first
    const int jx = t % TSX, ky = t / TSX;
    const int bx = 5  + ((jx & 1) ? ((jx+1)>>1) : -((jx+1)>>1));
    const int by = 40 + ((ky & 1) ? ((ky+1)>>1) : -((ky+1)>>1));

    const float wxmin = (float)(bx*32), wxmax = wxmin + 31.0f;
    const float wymin = (float)(by*4),  wymax = wymin + 3.0f;

    // two pixels per thread: px = yl*32 + xl
    const int pxa = lane, pxb = lane + 64;
    const float xA = (float)min(bx*32 + (pxa & 31), IMG_W-1);
    const float yA = (float)(by*4 + (pxa >> 5));
    const float xB = (float)min(bx*32 + (pxb & 31), IMG_W-1);
    const float yB = (float)(by*4 + (pxb >> 5));

    if (w < 2) Tcar[w*64 + lane] = 1.0f;    // carry-in transmittance

    // ---- build: 4-wave ballot compaction into hlist (order-preserving) ----
    const int g0 = w*128 + lane, g1 = g0 + 64;
    float4 b0 = bb[g0], b1 = bb[g1];
    bool h0 = !(b0.x > wxmax || b0.y < wxmin || b0.z > wymax || b0.w < wymin);
    bool h1 = !(b1.x > wxmax || b1.y < wxmin || b1.z > wymax || b1.w < wymin);
    unsigned long long m0 = __ballot(h0), m1 = __ballot(h1);
    int c0 = __popcll(m0), c1 = __popcll(m1);
    if (lane == 0) wcnt[w] = c0 + c1;
    __syncthreads();
    int offw = 0;
    #pragma unroll
    for (int k = 0; k < 4; ++k) if (k < w) offw += wcnt[k];
    const int nh = wcnt[0] + wcnt[1] + wcnt[2] + wcnt[3];
    if (h0) hlist[offw + __popcll(m0 & ltm)] = (unsigned short)g0;
    if (h1) hlist[offw + c0 + __popcll(m1 & ltm)] = (unsigned short)g1;
    __syncthreads();

    float dacA = 0.0f, dacB = 0.0f;        // per-thread depth partials
    f32x4 acc[2][8];
    #pragma unroll
    for (int m = 0; m < 2; ++m)
      #pragma unroll
      for (int n = 0; n < 8; ++n) acc[m][n] = (f32x4){0,0,0,0};

    for (int cb = 0; cb < nh; cb += CHUNK) {
      const int nc = min(CHUNK, nh - cb);

      // ---- 1a: araw + bf16 spec staging (zero-padded tail) ----
      #pragma unroll
      for (int tp = w; tp < CHUNK/2; tp += 4) {
        const int j0 = 2*tp, j1 = j0 + 1;
        float bA0=0.f, bB0=0.f, bA1=0.f, bB1=0.f;
        float s00=0.f, s01=0.f, s10=0.f, s11=0.f;
        if (j0 < nc) {
          int g = hlist[cb + j0];
          float4 q0 = *(const float4*)&ps[g*8];
          float4 q1 = *(const float4*)&ps[g*8+4];
          float dxA = xA - q0.x, dyA = yA - q0.y;
          bA0 = exp2f(q1.x - (q0.z*dxA*dxA + q0.w*dyA*dyA));
          float dxB = xB - q0.x, dyB = yB - q0.y;
          bB0 = exp2f(q1.x - (q0.z*dxB*dxB + q0.w*dyB*dyB));
          int sb = __float_as_int(q1.z);
          s00 = spec[sb + lane];
          if (lane < N_C - 64) s01 = spec[sb + 64 + lane];
          if (lane == 0) dep[j0] = q1.y;
        } else if (lane == 0) dep[j0] = 0.0f;
        if (j1 < nc) {
          int g = hlist[cb + j1];
          float4 q0 = *(const float4*)&ps[g*8];
          float4 q1 = *(const float4*)&ps[g*8+4];
          float dxA = xA - q0.x, dyA = yA - q0.y;
          bA1 = exp2f(q1.x - (q0.z*dxA*dxA + q0.w*dyA*dyA));
          float dxB = xB - q0.x, dyB = yB - q0.y;
          bB1 = exp2f(q1.x - (q0.z*dxB*dxB + q0.w*dyB*dyB));
          int sb = __float_as_int(q1.z);
          s10 = spec[sb + lane];
          if (lane < N_C - 64) s11 = spec[sb + 64 + lane];
          if (lane == 0) dep[j1] = q1.y;
        } else if (lane == 0) dep[j1] = 0.0f;
        buf[j0*128 + pxa] = bA0;  buf[j0*128 + pxb] = bB0;
        buf[j1*128 + pxa] = bA1;  buf[j1*128 + pxb] = bB1;
        // At rows = channels lane, 64+lane; column dword j0, xor-swizzled granule
        const int gsw = (((j0 >> 3) ^ (lane & 3)) << 3) | (j0 & 7);
        *(unsigned*)&At[lane*CHUNK + gsw]      = pk2(s00, s10);
        *(unsigned*)&At[(64+lane)*CHUNK + gsw] = pk2(s01, s11);
      }
      __syncthreads();   // A: buf/At/dep ready

      // ---- 1b: 4-wave segmented scan (8 serial steps/wave, 2 px/thread) ----
      {
        float tA = 1.0f, tB = 1.0f;
        float wvA[8], wvB[8];
        float ddA = 0.0f, ddB = 0.0f;
        const int jb = w*8;
        #pragma unroll
        for (int i = 0; i < 8; ++i) {
          const int j = jb + i;
          float aA = buf[j*128 + pxa], aB = buf[j*128 + pxb];
          float d  = dep[j];
          float vA = aA*tA; tA -= vA;
          float vB = aB*tB; tB -= vB;
          wvA[i] = vA; wvB[i] = vB;
          ddA = fmaf(d, vA, ddA); ddB = fmaf(d, vB, ddB);
        }
        seg[w][pxa] = tA; seg[w][pxb] = tB;
        __syncthreads();   // B: all segment totals in
        float pA = Tcar[pxa], pB = Tcar[pxb];   // prefix for this wave's segment
        float fA = pA, fB = pB;                 // full product (new carry)
        #pragma unroll
        for (int k = 0; k < 4; ++k) {
          float sA = seg[k][pxa], sB = seg[k][pxb];
          if (k < w) { pA *= sA; pB *= sB; }
          fA *= sA; fB *= sB;
        }
        dacA = fmaf(pA, ddA, dacA); dacB = fmaf(pB, ddB, dacB);
        union { bf16x8 v; unsigned u[4]; } kA, kB;
        #pragma unroll
        for (int i = 0; i < 8; i += 2) {
          kA.u[i>>1] = pk2(wvA[i]*pA, wvA[i+1]*pA);
          kB.u[i>>1] = pk2(wvB[i]*pB, wvB[i+1]*pB);
        }
        *(bf16x8*)&Bt[pxa*CHUNK + ((w ^ (pxa & 3)) << 3)] = kA.v;
        *(bf16x8*)&Bt[pxb*CHUNK + ((w ^ (pxb & 3)) << 3)] = kB.v;
        __syncthreads();   // C: Bt ready (Tcar reads done)
        if (w == 0) { Tcar[pxa] = fA; Tcar[pxb] = fB; }
      }

      // ---- 2: MFMA GEMM  D[c][px] += At * Bt  (K=32) ----
      {
        const int rA0 = mc0 + cl, rA1 = mc1 + cl;
        bf16x8 A0 = *(const bf16x8*)&At[rA0*CHUNK + ((quad ^ (rA0 & 3)) << 3)];
        bf16x8 A1 = *(const bf16x8*)&At[rA1*CHUNK + ((quad ^ (rA1 & 3)) << 3)];
        #pragma unroll
        for (int n = 0; n < 8; ++n) {
          const int rb = n*16 + cl;
          bf16x8 B = *(const bf16x8*)&Bt[rb*CHUNK + ((quad ^ (rb & 3)) << 3)];
          acc[0][n] = MFMA(A0, B, acc[0][n]);
          acc[1][n] = MFMA(A1, B, acc[1][n]);
        }
      }
      __syncthreads();   // D: LDS reusable next chunk (Tcar write visible)
    }

    // ---- epilogue ----
    dpar[w][pxa] = dacA; dpar[w][pxb] = dacB;
    __syncthreads();   // E

    #pragma unroll
    for (int m = 0; m < 2; ++m) {
      const int cc = w*32 + m*16 + quad*4;
      #pragma unroll
      for (int n = 0; n < 8; ++n) {
        const int px = n*16 + cl;
        const int x = bx*32 + (px & 31);
        if (x < IMG_W) {
          const int pixi = (by*4 + (px >> 5))*IMG_W + x;
          const float Tf = Tcar[px];
          f32x4 a = acc[m][n];
          if (cc+0 < N_C) out[(cc+0)*HW + pixi] = (a.x + Tf)*tmL[cc+0];
          if (cc+1 < N_C) out[(cc+1)*HW + pixi] = (a.y + Tf)*tmL[cc+1];
          if (cc+2 < N_C) out[(cc+2)*HW + pixi] = (a.z + Tf)*tmL[cc+2];
          if (cc+3 < N_C) out[(cc+3)*HW + pixi] = (a.w + Tf)*tmL[cc+3];
        }
      }
    }
    if (w < 2) {
      const int px = w*64 + lane;
      const int x = bx*32 + (px & 31);
      if (x < IMG_W) {
        const int pixi = (by*4 + (px >> 5))*IMG_W + x;
        out[N_C*HW + pixi] = dpar[0][px] + dpar[1][px] + dpar[2][px] + dpar[3][px];
        out[N_C*HW + HW + pixi] = 1.0f - Tcar[px];
      }
    }
    __syncthreads();   // F: protect LDS before next tile
  }
}

extern "C" void kernel_launch(void* const* d_in, const int* in_sizes, int n_in,
                              void* d_out, int out_size, void* d_ws, size_t ws_size,
                              hipStream_t stream) {
  const float* pos    = (const float*)d_in[0];
  // d_in[1] rotations: unused by the reference
  const float* scales = (const float*)d_in[2];
  const float* opac   = (const float*)d_in[3];
  const float* spec   = (const float*)d_in[4];
  const float* tm     = (const float*)d_in[5];
  const float* K      = (const float*)d_in[6];
  const float* E      = (const float*)d_in[7];
  float* out = (float*)d_out;

  float4* bb = (float4*)d_ws;
  float*  ps = (float*)(bb + N_G);
  int*    cnt = (int*)((char*)d_ws + N_G*16 + N_G*32);

  k_prep<<<1, 512, 0, stream>>>(pos, scales, opac, K, E, bb, ps, cnt);
  k_render<<<NBLK, 256, 0, stream>>>(bb, ps, cnt, spec, tm, out);
}